// Round 5
// baseline (242.845 us; speedup 1.0000x reference)
//
#include <hip/hip_runtime.h>

// DYSPN fused kernel — SCATTER formulation (each aff element read exactly once).
//
// out[b,h,w] = (G + att3)*cur/(S'+eps) + (1 - S_ppt/(S'+eps))*coarse
// with, for k = i*7+j (k != 24; CENTER_MASK kills the center tap):
//   S_ppt(h,w) = sum_k att[IDX[k]](h,w) * aff[k](h,w)        + att3
//   S'  (h,w)  = sum_k att[IDX[k]](h,w) * |aff[k]|(h,w)      + att3
//   G   (h,w)  = sum_k C_k(h+3-i, w+3-j),   C_k = att[IDX[k]] * aff[k]
// Scatter identity: C_k computed at the SOURCE pixel (own reads only) is
// scattered to target (src_row + i-3, src_col + j-3). Horizontal scatter is
// done per-lane into a 10-wide accumulator Hw[c+j] += C[c] and folded across
// lanes once per i (6 shuffles). Vertical scatter crosses waves via an LDS
// row-exchange per i. Contributions crossing the 8-row tile boundary are
// pre-summed into a 6-row spill buffer (d_ws) and applied by a tiny second
// kernel: out += spill * scale, scale = cur/denom (stored by kernel 1).

typedef float f32x4 __attribute__((ext_vector_type(4)));

constexpr int H = 256, W = 256, HW = H * W;
constexpr int P4 = HW / 4;    // plane stride in f32x4
constexpr int RW = W / 4;     // row stride in f32x4 (64)
constexpr int RB = 8;         // rows per tile (one wave per row)
constexpr int NT = H / RB;    // 32 tiles per image
constexpr int NG = 16 * NT;   // 512 tiles total

__global__ __launch_bounds__(512, 5) void dyspn_main(
    const float* __restrict__ aff,    // [B,49,H,W]
    const float* __restrict__ attn,   // [B,4,H,W]
    const float* __restrict__ cur,    // [B,1,H,W]
    const float* __restrict__ coarse, // [B,1,H,W]
    float* __restrict__ out,          // [B,1,H,W]
    float* __restrict__ scale,        // [B,H,W]  (ws)
    float* __restrict__ spill)        // [NG][6][W] (ws): rows 0-2 up, 3-5 down
{
    static constexpr int IDXR[7][7] = {
        {0,0,0,0,0,0,0},
        {0,1,1,1,1,1,0},
        {0,1,2,2,2,1,0},
        {0,1,2,3,2,1,0},
        {0,1,2,2,2,1,0},
        {0,1,1,1,1,1,0},
        {0,0,0,0,0,0,0}};

    __shared__ f32x4 sH[RB][RW];        // 8 KB: per-i row exchange
    __shared__ f32x4 sSp[2][3][RW];     // 6 KB: [0]=up-spill, [1]=down-spill

    const int g = blockIdx.x;
    const int b = g >> 5;               // batch
    const int t = g & 31;               // row-tile
    const int tid = threadIdx.x;
    const int r = tid >> 6;             // wave = row 0..7
    const int w = tid & 63;             // lane = col-group (4 cols)
    const int h = t * RB + r;

    const f32x4* __restrict__ aff4 = (const f32x4*)aff  + (size_t)b * 49 * P4;
    const f32x4* __restrict__ att4 = (const f32x4*)attn + (size_t)b * 4  * P4;
    const int hrow = h * RW;

    // zero spill accumulators
    if (tid < 2 * 3 * RW) {
        f32x4 z = {0.f, 0.f, 0.f, 0.f};
        ((f32x4*)sSp)[tid] = z;
    }
    __syncthreads();

    // own-pixel attention (the ONLY attention reads)
    f32x4 at_own[3], a3;
    at_own[0] = att4[0 * P4 + hrow + w];
    at_own[1] = att4[1 * P4 + hrow + w];
    at_own[2] = att4[2 * P4 + hrow + w];
    a3        = att4[3 * P4 + hrow + w];

    f32x4 sp = {0.f,0.f,0.f,0.f}, sa = {0.f,0.f,0.f,0.f}, G = {0.f,0.f,0.f,0.f};

#pragma unroll
    for (int i = 0; i < 7; ++i) {
        // Hw[e] accumulates contributions to target col 4w-3+e, e in [0,10)
        float Hw[10];
#pragma unroll
        for (int e = 0; e < 10; ++e) Hw[e] = 0.f;

#pragma unroll
        for (int j = 0; j < 7; ++j) {
            if (i == 3 && j == 3) continue;        // center tap masked
            const int k = i * 7 + j;
            const int idx = IDXR[i][j];
            f32x4 a  = aff4[k * P4 + hrow + w];    // the single read of plane k
            f32x4 wt = at_own[idx];
#pragma unroll
            for (int c = 0; c < 4; ++c) {
                float C = wt[c] * a[c];
                sp[c] += C;                               // S_ppt (own)
                sa[c]  = fmaf(wt[c], fabsf(a[c]), sa[c]); // S' (own)
                Hw[c + j] += C;                           // horizontal scatter
            }
        }

        // fold Hw across lanes: target own col 4w+c = own Hw[c+3]
        //   + left-neighbor Hw[c+7] (c<=2) + right-neighbor Hw[c-1] (c>=1)
        float L7 = __shfl(Hw[7], w - 1, 64);
        float L8 = __shfl(Hw[8], w - 1, 64);
        float L9 = __shfl(Hw[9], w - 1, 64);
        float R0 = __shfl(Hw[0], w + 1, 64);
        float R1 = __shfl(Hw[1], w + 1, 64);
        float R2 = __shfl(Hw[2], w + 1, 64);
        if (w == 0)  { L7 = 0.f; L8 = 0.f; L9 = 0.f; }
        if (w == 63) { R0 = 0.f; R1 = 0.f; R2 = 0.f; }
        f32x4 F;
        F[0] = Hw[3] + L7;
        F[1] = Hw[4] + L8 + R0;
        F[2] = Hw[5] + L9 + R1;
        F[3] = Hw[6] + R2;

        // vertical exchange: wave r's F targets tile-local row lt = r + i - 3
        __syncthreads();                 // WAR: previous i's sH reads done
        sH[r][w] = F;
        const int lt = r + i - 3;
        if (lt < 0) {                    // spills to tile above, its rows 5..7
            f32x4 v = sSp[0][lt + 3][w];
            sSp[0][lt + 3][w] = v + F;
        } else if (lt > 7) {             // spills to tile below, its rows 0..2
            f32x4 v = sSp[1][lt - 8][w];
            sSp[1][lt - 8][w] = v + F;
        }
        __syncthreads();                 // RAW: sH/spill writes visible
        const int src = r + 3 - i;       // wave whose F targets our row
        if ((unsigned)src < 8u) G += sH[src][w];
    }

    // export spill (6 rows x 256 cols per tile), fully written every call
    if (tid < 6 * RW) {
        int row  = tid / RW;             // 0..5
        int col4 = tid % RW;
        f32x4 v = (row < 3) ? sSp[0][row][col4] : sSp[1][row - 3][col4];
        ((f32x4*)(spill + (size_t)g * 6 * W))[row * RW + col4] = v;
    }

    // epilogue: local (in-tile) part of out, plus scale plane for the fix-up
    const f32x4* __restrict__ cur4 = (const f32x4*)cur    + (size_t)b * P4;
    const f32x4* __restrict__ cor4 = (const f32x4*)coarse + (size_t)b * P4;
    f32x4* __restrict__ out4       = (f32x4*)out          + (size_t)b * P4;
    f32x4* __restrict__ scl4       = (f32x4*)scale        + (size_t)b * P4;
    f32x4 cu = cur4[hrow + w];
    f32x4 co = cor4[hrow + w];
    f32x4 o, sc;
#pragma unroll
    for (int c = 0; c < 4; ++c) {
        float s_pr  = sa[c] + a3[c];
        float s_ppt = sp[c] + a3[c];
        float inv = 1.0f / (s_pr + 1e-6f);
        sc[c] = cu[c] * inv;
        o[c]  = (G[c] + a3[c]) * sc[c] + (1.f - s_ppt * inv) * co[c];
    }
    out4[hrow + w] = o;
    scl4[hrow + w] = sc;
}

// Apply cross-tile spill: rows 0..2 of tile t get tile (t-1)'s down-spill,
// rows 5..7 get tile (t+1)'s up-spill. out += spill * scale.
__global__ __launch_bounds__(256) void dyspn_fix(
    float* __restrict__ out, const float* __restrict__ scale,
    const float* __restrict__ spill)
{
    const int g = blockIdx.x;
    const int b = g >> 5, t = g & 31;
    const int col = threadIdx.x;
    const size_t obase = (size_t)b * HW;

    if (t > 0) {
#pragma unroll
        for (int row = 0; row < 3; ++row) {
            float v = spill[(size_t)(g - 1) * 6 * W + (3 + row) * W + col];
            int p = (t * RB + row) * W + col;
            out[obase + p] += v * scale[obase + p];
        }
    }
    if (t < NT - 1) {
#pragma unroll
        for (int row = 0; row < 3; ++row) {
            float v = spill[(size_t)(g + 1) * 6 * W + row * W + col];
            int p = (t * RB + 5 + row) * W + col;
            out[obase + p] += v * scale[obase + p];
        }
    }
}

extern "C" void kernel_launch(void* const* d_in, const int* in_sizes, int n_in,
                              void* d_out, int out_size, void* d_ws, size_t ws_size,
                              hipStream_t stream) {
    const float* aff    = (const float*)d_in[0];
    const float* attn   = (const float*)d_in[1];
    const float* cur    = (const float*)d_in[2];
    const float* coarse = (const float*)d_in[3];
    float* out = (float*)d_out;

    float* scale = (float*)d_ws;                 // 16*HW floats = 4 MiB
    float* spill = scale + (size_t)16 * HW;      // NG*6*W floats = 3 MiB

    hipLaunchKernelGGL(dyspn_main, dim3(NG), dim3(512), 0, stream,
                       aff, attn, cur, coarse, out, scale, spill);
    hipLaunchKernelGGL(dyspn_fix, dim3(NG), dim3(256), 0, stream,
                       out, scale, spill);
}

// Round 6
// 118.815 us; speedup vs baseline: 2.0439x; 2.0439x over previous
//
#include <hip/hip_runtime.h>

// DYSPN fused kernel — SCATTER formulation (each aff element read exactly once).
//
// out[b,h,w] = (G + att3)*cur/(S'+eps) + (1 - S_ppt/(S'+eps))*coarse
// with, for k = i*7+j (k != 24; CENTER_MASK kills the center tap):
//   S_ppt(h,w) = sum_k att[IDX[k]](h,w) * aff[k](h,w)        + att3
//   S'  (h,w)  = sum_k att[IDX[k]](h,w) * |aff[k]|(h,w)      + att3
//   G   (h,w)  = sum_k C_k(h+3-i, w+3-j),   C_k = att[IDX[k]] * aff[k]
// Scatter identity: C_k computed at the SOURCE pixel (own reads only) is
// scattered to target (src_row + i-3, src_col + j-3). Horizontal scatter is
// per-lane into a 10-wide accumulator Hw[c+j] += C[c], folded across lanes
// once per i (6 shuffles). Vertical scatter crosses waves via an LDS
// row-exchange per i. Contributions crossing the 8-row tile boundary are
// pre-summed into a 6-row spill buffer (d_ws) and applied by a tiny second
// kernel: out += spill * scale, scale = cur/denom (stored by kernel 1).
//
// R6 = R5 minus the __launch_bounds__ min-waves clause: (512,5) capped the
// kernel at 48 VGPRs and spilled ~430 MB/launch to scratch (WRITE_SIZE 439 MB
// vs 11 MB expected). Occupancy forcing caused the R2 disaster too — never
// cap VGPRs on a state-heavy kernel.

typedef float f32x4 __attribute__((ext_vector_type(4)));

constexpr int H = 256, W = 256, HW = H * W;
constexpr int P4 = HW / 4;    // plane stride in f32x4
constexpr int RW = W / 4;     // row stride in f32x4 (64)
constexpr int RB = 8;         // rows per tile (one wave per row)
constexpr int NT = H / RB;    // 32 tiles per image
constexpr int NG = 16 * NT;   // 512 tiles total

__global__ __launch_bounds__(512) void dyspn_main(
    const float* __restrict__ aff,    // [B,49,H,W]
    const float* __restrict__ attn,   // [B,4,H,W]
    const float* __restrict__ cur,    // [B,1,H,W]
    const float* __restrict__ coarse, // [B,1,H,W]
    float* __restrict__ out,          // [B,1,H,W]
    float* __restrict__ scale,        // [B,H,W]  (ws)
    float* __restrict__ spill)        // [NG][6][W] (ws): rows 0-2 up, 3-5 down
{
    static constexpr int IDXR[7][7] = {
        {0,0,0,0,0,0,0},
        {0,1,1,1,1,1,0},
        {0,1,2,2,2,1,0},
        {0,1,2,3,2,1,0},
        {0,1,2,2,2,1,0},
        {0,1,1,1,1,1,0},
        {0,0,0,0,0,0,0}};

    __shared__ f32x4 sH[RB][RW];        // 8 KB: per-i row exchange
    __shared__ f32x4 sSp[2][3][RW];     // 6 KB: [0]=up-spill, [1]=down-spill

    const int g = blockIdx.x;
    const int b = g >> 5;               // batch
    const int t = g & 31;               // row-tile
    const int tid = threadIdx.x;
    const int r = tid >> 6;             // wave = row 0..7
    const int w = tid & 63;             // lane = col-group (4 cols)
    const int h = t * RB + r;

    const f32x4* __restrict__ aff4 = (const f32x4*)aff  + (size_t)b * 49 * P4;
    const f32x4* __restrict__ att4 = (const f32x4*)attn + (size_t)b * 4  * P4;
    const int hrow = h * RW;

    // zero spill accumulators
    if (tid < 2 * 3 * RW) {
        f32x4 z = {0.f, 0.f, 0.f, 0.f};
        ((f32x4*)sSp)[tid] = z;
    }
    __syncthreads();

    // own-pixel attention (the ONLY attention reads)
    f32x4 at_own[3], a3;
    at_own[0] = att4[0 * P4 + hrow + w];
    at_own[1] = att4[1 * P4 + hrow + w];
    at_own[2] = att4[2 * P4 + hrow + w];
    a3        = att4[3 * P4 + hrow + w];

    f32x4 sp = {0.f,0.f,0.f,0.f}, sa = {0.f,0.f,0.f,0.f}, G = {0.f,0.f,0.f,0.f};

#pragma unroll
    for (int i = 0; i < 7; ++i) {
        // Hw[e] accumulates contributions to target col 4w-3+e, e in [0,10)
        float Hw[10];
#pragma unroll
        for (int e = 0; e < 10; ++e) Hw[e] = 0.f;

#pragma unroll
        for (int j = 0; j < 7; ++j) {
            if (i == 3 && j == 3) continue;        // center tap masked
            const int k = i * 7 + j;
            const int idx = IDXR[i][j];
            f32x4 a  = aff4[k * P4 + hrow + w];    // the single read of plane k
            f32x4 wt = at_own[idx];
#pragma unroll
            for (int c = 0; c < 4; ++c) {
                float C = wt[c] * a[c];
                sp[c] += C;                               // S_ppt (own)
                sa[c]  = fmaf(wt[c], fabsf(a[c]), sa[c]); // S' (own)
                Hw[c + j] += C;                           // horizontal scatter
            }
        }

        // fold Hw across lanes: target own col 4w+c = own Hw[c+3]
        //   + left-neighbor Hw[c+7] (c<=2) + right-neighbor Hw[c-1] (c>=1)
        float L7 = __shfl(Hw[7], w - 1, 64);
        float L8 = __shfl(Hw[8], w - 1, 64);
        float L9 = __shfl(Hw[9], w - 1, 64);
        float R0 = __shfl(Hw[0], w + 1, 64);
        float R1 = __shfl(Hw[1], w + 1, 64);
        float R2 = __shfl(Hw[2], w + 1, 64);
        if (w == 0)  { L7 = 0.f; L8 = 0.f; L9 = 0.f; }
        if (w == 63) { R0 = 0.f; R1 = 0.f; R2 = 0.f; }
        f32x4 F;
        F[0] = Hw[3] + L7;
        F[1] = Hw[4] + L8 + R0;
        F[2] = Hw[5] + L9 + R1;
        F[3] = Hw[6] + R2;

        // vertical exchange: wave r's F targets tile-local row lt = r + i - 3
        __syncthreads();                 // WAR: previous i's sH reads done
        sH[r][w] = F;
        const int lt = r + i - 3;
        if (lt < 0) {                    // spills to tile above, its rows 5..7
            f32x4 v = sSp[0][lt + 3][w];
            sSp[0][lt + 3][w] = v + F;
        } else if (lt > 7) {             // spills to tile below, its rows 0..2
            f32x4 v = sSp[1][lt - 8][w];
            sSp[1][lt - 8][w] = v + F;
        }
        __syncthreads();                 // RAW: sH/spill writes visible
        const int src = r + 3 - i;       // wave whose F targets our row
        if ((unsigned)src < 8u) G += sH[src][w];
    }

    // export spill (6 rows x 256 cols per tile), fully written every call
    if (tid < 6 * RW) {
        int row  = tid / RW;             // 0..5
        int col4 = tid % RW;
        f32x4 v = (row < 3) ? sSp[0][row][col4] : sSp[1][row - 3][col4];
        ((f32x4*)(spill + (size_t)g * 6 * W))[row * RW + col4] = v;
    }

    // epilogue: local (in-tile) part of out, plus scale plane for the fix-up
    const f32x4* __restrict__ cur4 = (const f32x4*)cur    + (size_t)b * P4;
    const f32x4* __restrict__ cor4 = (const f32x4*)coarse + (size_t)b * P4;
    f32x4* __restrict__ out4       = (f32x4*)out          + (size_t)b * P4;
    f32x4* __restrict__ scl4       = (f32x4*)scale        + (size_t)b * P4;
    f32x4 cu = cur4[hrow + w];
    f32x4 co = cor4[hrow + w];
    f32x4 o, sc;
#pragma unroll
    for (int c = 0; c < 4; ++c) {
        float s_pr  = sa[c] + a3[c];
        float s_ppt = sp[c] + a3[c];
        float inv = 1.0f / (s_pr + 1e-6f);
        sc[c] = cu[c] * inv;
        o[c]  = (G[c] + a3[c]) * sc[c] + (1.f - s_ppt * inv) * co[c];
    }
    out4[hrow + w] = o;
    scl4[hrow + w] = sc;
}

// Apply cross-tile spill: rows 0..2 of tile t get tile (t-1)'s down-spill,
// rows 5..7 get tile (t+1)'s up-spill. out += spill * scale.
__global__ __launch_bounds__(256) void dyspn_fix(
    float* __restrict__ out, const float* __restrict__ scale,
    const float* __restrict__ spill)
{
    const int g = blockIdx.x;
    const int b = g >> 5, t = g & 31;
    const int col = threadIdx.x;
    const size_t obase = (size_t)b * HW;

    if (t > 0) {
#pragma unroll
        for (int row = 0; row < 3; ++row) {
            float v = spill[(size_t)(g - 1) * 6 * W + (3 + row) * W + col];
            int p = (t * RB + row) * W + col;
            out[obase + p] += v * scale[obase + p];
        }
    }
    if (t < NT - 1) {
#pragma unroll
        for (int row = 0; row < 3; ++row) {
            float v = spill[(size_t)(g + 1) * 6 * W + row * W + col];
            int p = (t * RB + 5 + row) * W + col;
            out[obase + p] += v * scale[obase + p];
        }
    }
}

extern "C" void kernel_launch(void* const* d_in, const int* in_sizes, int n_in,
                              void* d_out, int out_size, void* d_ws, size_t ws_size,
                              hipStream_t stream) {
    const float* aff    = (const float*)d_in[0];
    const float* attn   = (const float*)d_in[1];
    const float* cur    = (const float*)d_in[2];
    const float* coarse = (const float*)d_in[3];
    float* out = (float*)d_out;

    float* scale = (float*)d_ws;                 // 16*HW floats = 4 MiB
    float* spill = scale + (size_t)16 * HW;      // NG*6*W floats = 3 MiB

    hipLaunchKernelGGL(dyspn_main, dim3(NG), dim3(512), 0, stream,
                       aff, attn, cur, coarse, out, scale, spill);
    hipLaunchKernelGGL(dyspn_fix, dim3(NG), dim3(256), 0, stream,
                       out, scale, spill);
}

// Round 7
// 51.330 us; speedup vs baseline: 4.7311x; 2.3147x over previous
//
#include <hip/hip_runtime.h>

// DYSPN fused kernel — SCATTER formulation (each aff element read exactly once).
//
// out[b,h,w] = (G + att3)*cur/(S'+eps) + (1 - S_ppt/(S'+eps))*coarse
// with, for k = i*7+j (k != 24; CENTER_MASK kills the center tap):
//   S_ppt(h,w) = sum_k att[IDX[k]](h,w) * aff[k](h,w)        + att3
//   S'  (h,w)  = sum_k att[IDX[k]](h,w) * |aff[k]|(h,w)      + att3
//   G   (h,w)  = sum_k C_k(h+3-i, w+3-j),   C_k = att[IDX[k]] * aff[k]
// C_k computed at the SOURCE pixel is scattered to (src_row+i-3, src_col+j-3):
// horizontally into a 10-wide per-lane accumulator Hw[c+j] (folded with 6
// shuffles per i), vertically via an LDS row-exchange per i. Contributions
// crossing the RB-row tile boundary go to a per-tile spill buffer (d_ws),
// applied by a tiny second kernel: out += spill * scale, scale = cur/denom.
//
// R7 vs R6: block 512->256 (RB 8->4). R6 spilled ~160 MB scratch because an
// 8-wave block caps the allocator at 128 VGPR while the pipelined unrolled
// body needs ~200. A 4-wave block + __launch_bounds__(256,1) raises the cap
// to 512 VGPR (permissive, NOT occupancy-forcing) -> no spill.

typedef float f32x4 __attribute__((ext_vector_type(4)));

constexpr int H = 256, W = 256, HW = H * W;
constexpr int P4 = HW / 4;    // plane stride in f32x4
constexpr int RW = W / 4;     // row stride in f32x4 (64)
constexpr int RB = 4;         // rows per tile (one wave per row)
constexpr int NT = H / RB;    // 64 tiles per image
constexpr int NG = 16 * NT;   // 1024 tiles total

__global__ __launch_bounds__(256, 1) void dyspn_main(
    const float* __restrict__ aff,    // [B,49,H,W]
    const float* __restrict__ attn,   // [B,4,H,W]
    const float* __restrict__ cur,    // [B,1,H,W]
    const float* __restrict__ coarse, // [B,1,H,W]
    float* __restrict__ out,          // [B,1,H,W]
    float* __restrict__ scale,        // [B,H,W]  (ws)
    float* __restrict__ spill)        // [NG][6][W] (ws): rows 0-2 up (lt=-3..-1),
                                      //                  rows 3-5 down (lt=RB..RB+2)
{
    static constexpr int IDXR[7][7] = {
        {0,0,0,0,0,0,0},
        {0,1,1,1,1,1,0},
        {0,1,2,2,2,1,0},
        {0,1,2,3,2,1,0},
        {0,1,2,2,2,1,0},
        {0,1,1,1,1,1,0},
        {0,0,0,0,0,0,0}};

    __shared__ f32x4 sH[RB][RW];        // 4 KB: per-i row exchange
    __shared__ f32x4 sSp[2][3][RW];     // 6 KB: [0]=up-spill, [1]=down-spill

    const int g = blockIdx.x;
    const int b = g >> 6;               // batch
    const int t = g & 63;               // row-tile
    const int tid = threadIdx.x;
    const int r = tid >> 6;             // wave = row 0..3
    const int w = tid & 63;             // lane = col-group (4 cols)
    const int h = t * RB + r;

    const f32x4* __restrict__ aff4 = (const f32x4*)aff  + (size_t)b * 49 * P4;
    const f32x4* __restrict__ att4 = (const f32x4*)attn + (size_t)b * 4  * P4;
    const int hrow = h * RW;

    // zero spill accumulators (2*3*RW = 384 f32x4, 256 threads -> 2 passes)
    {
        f32x4 z = {0.f, 0.f, 0.f, 0.f};
        for (int zi = tid; zi < 2 * 3 * RW; zi += 256) ((f32x4*)sSp)[zi] = z;
    }
    __syncthreads();

    // own-pixel attention (the ONLY attention reads in the main loop)
    f32x4 at_own[3];
    at_own[0] = att4[0 * P4 + hrow + w];
    at_own[1] = att4[1 * P4 + hrow + w];
    at_own[2] = att4[2 * P4 + hrow + w];

    f32x4 sp = {0.f,0.f,0.f,0.f}, sa = {0.f,0.f,0.f,0.f}, G = {0.f,0.f,0.f,0.f};

#pragma unroll
    for (int i = 0; i < 7; ++i) {
        // Hw[e] accumulates contributions to target col 4w-3+e, e in [0,10)
        float Hw[10];
#pragma unroll
        for (int e = 0; e < 10; ++e) Hw[e] = 0.f;

#pragma unroll
        for (int j = 0; j < 7; ++j) {
            if (i == 3 && j == 3) continue;        // center tap masked
            const int k = i * 7 + j;
            const int idx = IDXR[i][j];
            f32x4 a  = aff4[k * P4 + hrow + w];    // the single read of plane k
            f32x4 wt = at_own[idx];
#pragma unroll
            for (int c = 0; c < 4; ++c) {
                float C = wt[c] * a[c];
                sp[c] += C;                               // S_ppt (own)
                sa[c]  = fmaf(wt[c], fabsf(a[c]), sa[c]); // S' (own)
                Hw[c + j] += C;                           // horizontal scatter
            }
        }

        // fold Hw across lanes: target own col 4w+c = own Hw[c+3]
        //   + left-neighbor Hw[c+7] (c<=2) + right-neighbor Hw[c-1] (c>=1)
        float L7 = __shfl(Hw[7], w - 1, 64);
        float L8 = __shfl(Hw[8], w - 1, 64);
        float L9 = __shfl(Hw[9], w - 1, 64);
        float R0 = __shfl(Hw[0], w + 1, 64);
        float R1 = __shfl(Hw[1], w + 1, 64);
        float R2 = __shfl(Hw[2], w + 1, 64);
        if (w == 0)  { L7 = 0.f; L8 = 0.f; L9 = 0.f; }
        if (w == 63) { R0 = 0.f; R1 = 0.f; R2 = 0.f; }
        f32x4 F;
        F[0] = Hw[3] + L7;
        F[1] = Hw[4] + L8 + R0;
        F[2] = Hw[5] + L9 + R1;
        F[3] = Hw[6] + R2;

        // vertical exchange: wave r's F targets tile-local row lt = r + i - 3
        __syncthreads();                 // WAR: previous i's sH reads done
        sH[r][w] = F;
        const int lt = r + i - 3;        // in [-3, RB+2]
        if (lt < 0) {                    // spills to tile above (its rows RB+lt)
            f32x4 v = sSp[0][lt + 3][w];
            sSp[0][lt + 3][w] = v + F;
        } else if (lt > RB - 1) {        // spills to tile below (its rows lt-RB)
            f32x4 v = sSp[1][lt - RB][w];
            sSp[1][lt - RB][w] = v + F;
        }
        __syncthreads();                 // RAW: sH/spill writes visible
        const int src = r + 3 - i;       // wave whose F targets our row
        if ((unsigned)src < (unsigned)RB) G += sH[src][w];
    }

    // export spill (6 rows x 256 cols per tile), fully written every call
    for (int zi = tid; zi < 6 * RW; zi += 256) {
        int row  = zi / RW;              // 0..5
        int col4 = zi % RW;
        f32x4 v = (row < 3) ? sSp[0][row][col4] : sSp[1][row - 3][col4];
        ((f32x4*)(spill + (size_t)g * 6 * W))[row * RW + col4] = v;
    }

    // epilogue: local (in-tile) part of out, plus scale plane for the fix-up
    f32x4 a3 = att4[3 * P4 + hrow + w];
    const f32x4* __restrict__ cur4 = (const f32x4*)cur    + (size_t)b * P4;
    const f32x4* __restrict__ cor4 = (const f32x4*)coarse + (size_t)b * P4;
    f32x4* __restrict__ out4       = (f32x4*)out          + (size_t)b * P4;
    f32x4* __restrict__ scl4       = (f32x4*)scale        + (size_t)b * P4;
    f32x4 cu = cur4[hrow + w];
    f32x4 co = cor4[hrow + w];
    f32x4 o, sc;
#pragma unroll
    for (int c = 0; c < 4; ++c) {
        float s_pr  = sa[c] + a3[c];
        float s_ppt = sp[c] + a3[c];
        float inv = 1.0f / (s_pr + 1e-6f);
        sc[c] = cu[c] * inv;
        o[c]  = (G[c] + a3[c]) * sc[c] + (1.f - s_ppt * inv) * co[c];
    }
    out4[hrow + w] = o;
    scl4[hrow + w] = sc;
}

// Apply cross-tile spill. Tile t (rows [RB*t, RB*t+RB)):
//   local rows 0..2 += tile(t-1).down[0..2]   (its lt=RB..RB+2)
//   local rows 1..3 += tile(t+1).up[0..2]     (its lt=-3..-1 -> local 1..3)
__global__ __launch_bounds__(256) void dyspn_fix(
    float* __restrict__ out, const float* __restrict__ scale,
    const float* __restrict__ spill)
{
    const int g = blockIdx.x;
    const int b = g >> 6, t = g & 63;
    const int col = threadIdx.x;
    const size_t obase = (size_t)b * HW;

    if (t > 0) {
#pragma unroll
        for (int row = 0; row < 3; ++row) {
            float v = spill[(size_t)(g - 1) * 6 * W + (3 + row) * W + col];
            int p = (t * RB + row) * W + col;
            out[obase + p] += v * scale[obase + p];
        }
    }
    if (t < NT - 1) {
#pragma unroll
        for (int row = 0; row < 3; ++row) {
            float v = spill[(size_t)(g + 1) * 6 * W + row * W + col];
            int p = (t * RB + 1 + row) * W + col;
            out[obase + p] += v * scale[obase + p];
        }
    }
}

extern "C" void kernel_launch(void* const* d_in, const int* in_sizes, int n_in,
                              void* d_out, int out_size, void* d_ws, size_t ws_size,
                              hipStream_t stream) {
    const float* aff    = (const float*)d_in[0];
    const float* attn   = (const float*)d_in[1];
    const float* cur    = (const float*)d_in[2];
    const float* coarse = (const float*)d_in[3];
    float* out = (float*)d_out;

    float* scale = (float*)d_ws;                 // 16*HW floats = 4 MiB
    float* spill = scale + (size_t)16 * HW;      // NG*6*W floats = 6 MiB

    hipLaunchKernelGGL(dyspn_main, dim3(NG), dim3(256), 0, stream,
                       aff, attn, cur, coarse, out, scale, spill);
    hipLaunchKernelGGL(dyspn_fix, dim3(NG), dim3(256), 0, stream,
                       out, scale, spill);
}